// Round 5
// baseline (4906.766 us; speedup 1.0000x reference)
//
#include <hip/hip_runtime.h>

#define BATCH 64
#define TIN   49
#define NB    24
#define HID   384
#define SOUT  10
#define NGATE 5

typedef __attribute__((ext_vector_type(4))) float f32x4;
typedef __attribute__((ext_vector_type(8))) short short8v;

__device__ __forceinline__ unsigned short f2bf(float f) {
    union { float f; unsigned u; } v; v.f = f;
    unsigned r = v.u + 0x7fffu + ((v.u >> 16) & 1u);   // round-nearest-even
    return (unsigned short)(r >> 16);
}
__device__ __forceinline__ float bf2f(unsigned short h) {
    union { unsigned u; float f; } v; v.u = ((unsigned)h) << 16; return v.f;
}

#define NW_BLK 51840
#define NP_BLK 23040
#define NM_BLK 576
#define NITEMS 11520   // 480 cell-instances x 24 col-tiles

// ---------------------------------------------------------------------------
// Fused prologue: pack_w + pack_p + init_means in one dispatch.
// ---------------------------------------------------------------------------
__global__ __launch_bounds__(256) void prologue_kernel(
    const float* __restrict__ U, const float* __restrict__ Wt,
    const float* __restrict__ Ws, const float* __restrict__ p,
    const float* __restrict__ hid, const float* __restrict__ cel,
    const float* __restrict__ gt,
    unsigned short* __restrict__ wpack, unsigned short* __restrict__ pb,
    unsigned short* __restrict__ hp_b, float* __restrict__ cp_f)
{
    int bx = blockIdx.x;
    if (bx < NW_BLK) {
        // wpack[(((cell*24+t)*5+g)*36+kc)*64 + lane][8]
        //   elem j: B[k=kc*32+(lane>>4)*8+j][col=t*16+(lane&15)], m=k/384 -> U/Wt/Ws
        size_t tid = (size_t)bx * 256 + threadIdx.x;       // 13,271,040
        int l = (int)(tid & 63); size_t q = tid >> 6;
        int kc = (int)(q % 36); q /= 36;
        int g  = (int)(q % NGATE); q /= NGATE;
        int t  = (int)(q % 24); q /= 24;
        int cell = (int)q;                                 // r*NB+n, 0..47
        int m = kc / 12;
        int kk0 = (kc % 12) * 32 + (l >> 4) * 8;
        int col = t * 16 + (l & 15);
        const float* W = (m == 0) ? U : (m == 1) ? Wt : Ws;
        const float* src = W + ((size_t)(cell * NGATE + g) * HID + kk0) * HID + col;
        unsigned short o[8];
#pragma unroll
        for (int j = 0; j < 8; ++j) o[j] = f2bf(src[(size_t)j * HID]);
        *(short8v*)(wpack + tid * 8) = *(const short8v*)o;
    } else if (bx < NW_BLK + NP_BLK) {
        // p f32 [B][SOUT][NB][H] -> bf16 [SOUT][NB][B][H]
        size_t idx = (size_t)(bx - NW_BLK) * 256 + threadIdx.x;  // 5,898,240
        int h = (int)(idx % HID);
        size_t q = idx / HID;
        int b = (int)(q % BATCH); q /= BATCH;
        int n = (int)(q % NB); q /= NB;
        int f = (int)q;
        pb[idx] = f2bf(p[((size_t)(b * SOUT + f) * NB + n) * HID + h]);
    } else {
        // temporal means -> hp (bf16) + cp (f32), layout [r][n][b][h]
        int idx = (bx - NW_BLK - NP_BLK) * 256 + threadIdx.x;    // 147,456
        const int total4 = NB * BATCH * HID / 4;
        if (idx >= total4) return;
        const int H4 = HID / 4;
        int h = (idx % H4) * 4;
        int b = (idx / H4) % BATCH;
        int n = idx / (H4 * BATCH);
        const int fs4 = NB * HID / 4;
        const float4* ph = (const float4*)(hid + ((size_t)b * TIN * NB + n) * HID + h);
        const float4* pc = (const float4*)(cel + ((size_t)b * TIN * NB + n) * HID + h);
        float sh[4] = {0,0,0,0}, sc[4] = {0,0,0,0};
        for (int t = 0; t < TIN; ++t) {
            float4 vh = ph[(size_t)t * fs4];
            float4 vc = pc[(size_t)t * fs4];
            sh[0] += vh.x; sh[1] += vh.y; sh[2] += vh.z; sh[3] += vh.w;
            sc[0] += vc.x; sc[1] += vc.y; sc[2] += vc.z; sc[3] += vc.w;
        }
        float4 g4 = *(const float4*)(gt + ((size_t)b * NB + n) * HID + h);
        const float* g_ = (const float*)&g4;
        unsigned short o0[4], o1[4];
        float c0[4];
#pragma unroll
        for (int j = 0; j < 4; ++j) {
            o0[j] = f2bf(sh[j] / TIN);
            o1[j] = f2bf((g_[j] + sh[j]) / (TIN + 1));
            c0[j] = sc[j] / TIN;
        }
        size_t base = (size_t)idx * 4;
        const size_t tot = (size_t)NB * BATCH * HID;
        *(uint2*)(hp_b + base)       = *(const uint2*)o0;
        *(uint2*)(hp_b + tot + base) = *(const uint2*)o1;
        *(float4*)(cp_f + base)       = make_float4(c0[0], c0[1], c0[2], c0[3]);
        *(float4*)(cp_f + tot + base) = make_float4(c0[0], c0[1], c0[2], c0[3]);
    }
}

// spatial boundary: mean over bones of the r=0 init states
__global__ void init_bounds_kernel(const unsigned short* __restrict__ hp_b,
                                   const float* __restrict__ cp_f,
                                   unsigned short* __restrict__ bh_b,
                                   float* __restrict__ bc_f) {
    int idx = blockIdx.x * blockDim.x + threadIdx.x;       // BATCH*HID
    if (idx >= BATCH * HID) return;
    float sh = 0.f, sc = 0.f;
    for (int n = 0; n < NB; ++n) {
        sh += bf2f(hp_b[(size_t)n * BATCH * HID + idx]);
        sc += cp_f[(size_t)n * BATCH * HID + idx];
    }
    bh_b[idx] = f2bf(sh / NB);
    bc_f[idx] = sc / NB;
}

__global__ void reset_kernel(int* flags) {
    int i = blockIdx.x * blockDim.x + threadIdx.x;
    if (i < 2 * NB * SOUT + 1) flags[i] = 0;
}

// ---------------------------------------------------------------------------
// Persistent dataflow kernel. 256 blocks (1/CU, co-resident) x 640 threads
// (10 waves: gate=w%5, K-half=w/5). Work items = (cell r,n,f; col-tile t),
// pulled via a global ticket in topological order (key 2*(f+n)+r), so the
// minimal in-progress ticket always has all deps satisfied -> no deadlock.
// Producers publish per-cell done-counters with agent-scope release adds;
// consumers spin on acquire loads. State arrays fully indexed [r][n][f].
// ---------------------------------------------------------------------------
__global__ __launch_bounds__(640) void persist_kernel(
    const unsigned short* __restrict__ pb,
    const unsigned short* __restrict__ wpack,
    const float* __restrict__ bias,
    const unsigned short* __restrict__ hp_b,
    const float* __restrict__ cp_f,
    const unsigned short* __restrict__ bh_b,
    const float* __restrict__ bc_f,
    unsigned short* __restrict__ h_st,   // [2][NB][SOUT][64][384] bf16
    float* __restrict__ c_st,            // same shape f32
    float* __restrict__ out,
    int* __restrict__ done,              // [2*NB*SOUT]
    int* __restrict__ tick)
{
    const int wv   = threadIdx.x >> 6;
    const int gate = wv % NGATE;
    const int kh   = wv / NGATE;
    const int lane = threadIdx.x & 63;
    const int S = BATCH * HID;

    __shared__ int s_tkt;
    __shared__ float gl[2][NGATE][64][17];

    for (;;) {
        __syncthreads();
        if (threadIdx.x == 0)
            s_tkt = __hip_atomic_fetch_add(tick, 1, __ATOMIC_RELAXED,
                                           __HIP_MEMORY_SCOPE_AGENT);
        __syncthreads();
        const int T = s_tkt;
        if (T >= NITEMS) return;

        // ---- decode ticket -> (r, n, f, t) in topo order
        int rem = T, r = 0, lo = 0, d = 0;
        for (int s = 0;; ++s) {
            d = s >> 1; r = s & 1;
            lo = d - (SOUT - 1); if (lo < 0) lo = 0;
            int hi = (d < NB - 1) ? d : NB - 1;
            int c = (hi - lo + 1) * 24;
            if (rem < c) break;
            rem -= c;
        }
        const int n = lo + rem / 24;
        const int t = rem % 24;
        const int f = d - n;
        const int cell = r * NB + n;
        const int ci = cell * SOUT + f;

        // ---- dependency spin (acquire)
        int dep0 = -1, dep1 = -1, dep2 = -1;
        if (r == 0) {
            if (f > 0) dep0 = n * SOUT + f - 1;
            if (n > 0) dep1 = (n - 1) * SOUT + f;
        } else {
            dep0 = n * SOUT + f;
            if (f > 0) dep1 = (NB + n) * SOUT + f - 1;
            if (n > 0) dep2 = (NB + n - 1) * SOUT + f;
        }
        if (dep0 >= 0)
            while (__hip_atomic_load(done + dep0, __ATOMIC_ACQUIRE,
                                     __HIP_MEMORY_SCOPE_AGENT) < 24)
                __builtin_amdgcn_s_sleep(2);
        if (dep1 >= 0)
            while (__hip_atomic_load(done + dep1, __ATOMIC_ACQUIRE,
                                     __HIP_MEMORY_SCOPE_AGENT) < 24)
                __builtin_amdgcn_s_sleep(2);
        if (dep2 >= 0)
            while (__hip_atomic_load(done + dep2, __ATOMIC_ACQUIRE,
                                     __HIP_MEMORY_SCOPE_AGENT) < 24)
                __builtin_amdgcn_s_sleep(2);

        // ---- operand base pointers
        const unsigned short *xb, *htb, *hsb;
        const float *ctb, *csb;
        if (r == 0) {
            xb  = pb + (size_t)(f * NB + n) * S;
            htb = f ? h_st + (size_t)(n * SOUT + f - 1) * S : hp_b + (size_t)n * S;
            hsb = n ? h_st + (size_t)((n - 1) * SOUT + f) * S : bh_b;
            ctb = f ? c_st + (size_t)(n * SOUT + f - 1) * S : cp_f + (size_t)n * S;
            csb = n ? c_st + (size_t)((n - 1) * SOUT + f) * S : bc_f;
        } else {
            xb  = h_st + (size_t)(n * SOUT + f) * S;        // h0 of this cell
            htb = f ? h_st + (size_t)((NB + n) * SOUT + f - 1) * S
                    : hp_b + (size_t)(NB + n) * S;
            hsb = n ? h_st + (size_t)((NB + n - 1) * SOUT + f) * S : bh_b;
            ctb = f ? c_st + (size_t)((NB + n) * SOUT + f - 1) * S
                    : cp_f + (size_t)(NB + n) * S;
            csb = n ? c_st + (size_t)((NB + n - 1) * SOUT + f) * S : bc_f;
        }

        // ---- epilogue operands issued early (latency hides under MFMA)
        float4 ct4, cs4;
        float4 bg[NGATE];
        const int eb = threadIdx.x >> 2;
        const int ec0 = (threadIdx.x & 3) * 4;
        const int ecol = t * 16 + ec0;
        if (threadIdx.x < 256) {
            ct4 = *(const float4*)(ctb + (size_t)eb * HID + ecol);
            cs4 = *(const float4*)(csb + (size_t)eb * HID + ecol);
            const float* bbb = bias + (size_t)cell * NGATE * HID + ecol;
#pragma unroll
            for (int g = 0; g < NGATE; ++g) bg[g] = *(const float4*)(bbb + g * HID);
        }

        const short8v* wpB = (const short8v*)wpack
            + (size_t)((cell * 24 + t) * NGATE + gate) * 36 * 64
            + (size_t)kh * 18 * 64 + lane;

        const int rl = lane & 15;
        const int kg = (lane >> 4) * 8;
        const unsigned short* s0 = xb  + (size_t)rl * HID + kg;
        const unsigned short* s1 = htb + (size_t)rl * HID + kg;
        const unsigned short* s2 = hsb + (size_t)rl * HID + kg;

        auto addrA = [&](int s) -> const unsigned short* {
            if (kh == 0) return (s < 12) ? s0 + s * 32 : s1 + (s - 12) * 32;
            else         return (s < 6)  ? s1 + (s + 6) * 32 : s2 + (s - 6) * 32;
        };

        f32x4 acc0 = {0,0,0,0}, acc1 = {0,0,0,0}, acc2 = {0,0,0,0}, acc3 = {0,0,0,0};

        constexpr int PF = 4;
        short8v bb[PF];
        short8v aa[PF][4];
#pragma unroll
        for (int s = 0; s < PF; ++s) {
            bb[s] = wpB[(size_t)s * 64];
            const unsigned short* ap = addrA(s);
            aa[s][0] = *(const short8v*)(ap);
            aa[s][1] = *(const short8v*)(ap + 16 * HID);
            aa[s][2] = *(const short8v*)(ap + 32 * HID);
            aa[s][3] = *(const short8v*)(ap + 48 * HID);
        }
#pragma unroll
        for (int s = 0; s < 18; ++s) {
            const int slot = s & (PF - 1);
            short8v b_ = bb[slot];
            acc0 = __builtin_amdgcn_mfma_f32_16x16x32_bf16(aa[slot][0], b_, acc0, 0, 0, 0);
            acc1 = __builtin_amdgcn_mfma_f32_16x16x32_bf16(aa[slot][1], b_, acc1, 0, 0, 0);
            acc2 = __builtin_amdgcn_mfma_f32_16x16x32_bf16(aa[slot][2], b_, acc2, 0, 0, 0);
            acc3 = __builtin_amdgcn_mfma_f32_16x16x32_bf16(aa[slot][3], b_, acc3, 0, 0, 0);
            if (s + PF < 18) {
                const int nx = s + PF;
                bb[slot] = wpB[(size_t)nx * 64];
                const unsigned short* ap = addrA(nx);
                aa[slot][0] = *(const short8v*)(ap);
                aa[slot][1] = *(const short8v*)(ap + 16 * HID);
                aa[slot][2] = *(const short8v*)(ap + 32 * HID);
                aa[slot][3] = *(const short8v*)(ap + 48 * HID);
            }
        }

        {
            int rb = (lane >> 4) * 4;
#pragma unroll
            for (int i = 0; i < 4; ++i) {
                gl[kh][gate][rb + i +  0][rl] = acc0[i];
                gl[kh][gate][rb + i + 16][rl] = acc1[i];
                gl[kh][gate][rb + i + 32][rl] = acc2[i];
                gl[kh][gate][rb + i + 48][rl] = acc3[i];
            }
        }
        __syncthreads();

        if (threadIdx.x < 256) {
            const float* ct_ = (const float*)&ct4;
            const float* cs_ = (const float*)&cs4;
            size_t doff = (size_t)ci * S + (size_t)eb * HID + ecol;
            unsigned short* hd = h_st + doff;
            float* cd = c_st + doff;

            float hv4[4], ch4[4];
#pragma unroll
            for (int cc = 0; cc < 4; ++cc) {
                int c = ec0 + cc;
                float gi  = gl[0][0][eb][c] + gl[1][0][eb][c] + ((const float*)&bg[0])[cc];
                float gfs = gl[0][1][eb][c] + gl[1][1][eb][c] + ((const float*)&bg[1])[cc];
                float gft = gl[0][2][eb][c] + gl[1][2][eb][c] + ((const float*)&bg[2])[cc];
                float go  = gl[0][3][eb][c] + gl[1][3][eb][c] + ((const float*)&bg[3])[cc];
                float gc  = gl[0][4][eb][c] + gl[1][4][eb][c] + ((const float*)&bg[4])[cc];
                float i_n = 1.f / (1.f + __expf(-gi));
                float f_s = 1.f / (1.f + __expf(-gfs));
                float f_t = 1.f / (1.f + __expf(-gft));
                float o_n = 1.f / (1.f + __expf(-go));
                float c_n = tanhf(gc);
                float ch  = i_n * c_n + f_t * ct_[cc] + f_s * cs_[cc];
                float hv  = o_n * tanhf(ch);
                hv4[cc] = hv; ch4[cc] = ch;
                hd[cc] = f2bf(hv);
            }
            *(float4*)cd = make_float4(ch4[0], ch4[1], ch4[2], ch4[3]);
            if (r == 1) {
                size_t o = ((size_t)(eb * SOUT + f) * NB + n) * HID + ecol;
                *(float4*)(out + o) = make_float4(hv4[0], hv4[1], hv4[2], hv4[3]);
                *(float4*)(out + (size_t)BATCH * SOUT * NB * HID + o)
                    = make_float4(ch4[0], ch4[1], ch4[2], ch4[3]);
            }
        }
        __syncthreads();
        if (threadIdx.x == 0)
            __hip_atomic_fetch_add(done + ci, 1, __ATOMIC_RELEASE,
                                   __HIP_MEMORY_SCOPE_AGENT);
    }
}

// ---------------------------------------------------------------------------
extern "C" void kernel_launch(void* const* d_in, const int* in_sizes, int n_in,
                              void* d_out, int out_size, void* d_ws, size_t ws_size,
                              hipStream_t stream) {
    const float* hid  = (const float*)d_in[0];
    const float* cel  = (const float*)d_in[1];
    const float* gt   = (const float*)d_in[2];
    // d_in[3] global_s_state: unused by the reference
    const float* p    = (const float*)d_in[4];
    const float* U    = (const float*)d_in[5];
    const float* Wt   = (const float*)d_in[6];
    const float* Ws   = (const float*)d_in[7];
    const float* bias = (const float*)d_in[8];
    float* out = (float*)d_out;

    char* cur_ = (char*)d_ws;
    auto carve = [&](size_t bytes) -> void* {
        void* r = cur_; cur_ += (bytes + 255) & ~(size_t)255; return r;
    };
    const size_t NPBH = (size_t)NB * BATCH * HID;
    unsigned short* wpack = (unsigned short*)carve((size_t)13271040 * 16); // 212 MB
    unsigned short* pb    = (unsigned short*)carve((size_t)SOUT * NB * BATCH * HID * 2);
    unsigned short* hp_b  = (unsigned short*)carve(2 * NPBH * 2);
    float*          cp_f  = (float*)carve(2 * NPBH * 4);
    unsigned short* bh_b  = (unsigned short*)carve((size_t)BATCH * HID * 2);
    float*          bc_f  = (float*)carve((size_t)BATCH * HID * 4);
    unsigned short* h_st  = (unsigned short*)carve((size_t)2 * NB * SOUT * BATCH * HID * 2);
    float*          c_st  = (float*)carve((size_t)2 * NB * SOUT * BATCH * HID * 4);
    int*            flags = (int*)carve((2 * NB * SOUT + 1) * sizeof(int));

    reset_kernel<<<2, 256, 0, stream>>>(flags);
    prologue_kernel<<<NW_BLK + NP_BLK + NM_BLK, 256, 0, stream>>>(
        U, Wt, Ws, p, hid, cel, gt, wpack, pb, hp_b, cp_f);
    init_bounds_kernel<<<(BATCH * HID + 255) / 256, 256, 0, stream>>>(
        hp_b, cp_f, bh_b, bc_f);
    persist_kernel<<<256, 640, 0, stream>>>(
        pb, wpack, bias, hp_b, cp_f, bh_b, bc_f,
        h_st, c_st, out, flags, flags + 2 * NB * SOUT);
}

// Round 6
// 1997.383 us; speedup vs baseline: 2.4566x; 2.4566x over previous
//
#include <hip/hip_runtime.h>

#define BATCH 64
#define TIN   49
#define NB    24
#define HID   384
#define SOUT  10
#define NGATE 5

typedef __attribute__((ext_vector_type(4))) float f32x4;
typedef __attribute__((ext_vector_type(8))) short short8v;

__device__ __forceinline__ unsigned short f2bf(float f) {
    union { float f; unsigned u; } v; v.f = f;
    unsigned r = v.u + 0x7fffu + ((v.u >> 16) & 1u);   // round-nearest-even
    return (unsigned short)(r >> 16);
}
__device__ __forceinline__ float bf2f(unsigned short h) {
    union { unsigned u; float f; } v; v.u = ((unsigned)h) << 16; return v.f;
}

#define NW_BLK 51840
#define NP_BLK 23040
#define NM_BLK 576
#define NITEMS 11520   // 480 cell-instances x 24 col-tiles
#define PGRID  512     // persistent blocks: 2/CU, fully resident

// ---------------------------------------------------------------------------
// Fused prologue: pack_w + pack_p + init_means in one dispatch.
// ---------------------------------------------------------------------------
__global__ __launch_bounds__(256) void prologue_kernel(
    const float* __restrict__ U, const float* __restrict__ Wt,
    const float* __restrict__ Ws, const float* __restrict__ p,
    const float* __restrict__ hid, const float* __restrict__ cel,
    const float* __restrict__ gt,
    unsigned short* __restrict__ wpack, unsigned short* __restrict__ pb,
    unsigned short* __restrict__ hp_b, float* __restrict__ cp_f)
{
    int bx = blockIdx.x;
    if (bx < NW_BLK) {
        // wpack[(((cell*24+t)*5+g)*36+kc)*64 + lane][8]
        //   elem j: B[k=kc*32+(lane>>4)*8+j][col=t*16+(lane&15)], m=k/384 -> U/Wt/Ws
        size_t tid = (size_t)bx * 256 + threadIdx.x;       // 13,271,040
        int l = (int)(tid & 63); size_t q = tid >> 6;
        int kc = (int)(q % 36); q /= 36;
        int g  = (int)(q % NGATE); q /= NGATE;
        int t  = (int)(q % 24); q /= 24;
        int cell = (int)q;                                 // r*NB+n, 0..47
        int m = kc / 12;
        int kk0 = (kc % 12) * 32 + (l >> 4) * 8;
        int col = t * 16 + (l & 15);
        const float* W = (m == 0) ? U : (m == 1) ? Wt : Ws;
        const float* src = W + ((size_t)(cell * NGATE + g) * HID + kk0) * HID + col;
        unsigned short o[8];
#pragma unroll
        for (int j = 0; j < 8; ++j) o[j] = f2bf(src[(size_t)j * HID]);
        *(short8v*)(wpack + tid * 8) = *(const short8v*)o;
    } else if (bx < NW_BLK + NP_BLK) {
        // p f32 [B][SOUT][NB][H] -> bf16 [SOUT][NB][B][H]
        size_t idx = (size_t)(bx - NW_BLK) * 256 + threadIdx.x;  // 5,898,240
        int h = (int)(idx % HID);
        size_t q = idx / HID;
        int b = (int)(q % BATCH); q /= BATCH;
        int n = (int)(q % NB); q /= NB;
        int f = (int)q;
        pb[idx] = f2bf(p[((size_t)(b * SOUT + f) * NB + n) * HID + h]);
    } else {
        // temporal means -> hp (bf16) + cp (f32), layout [r][n][b][h]
        int idx = (bx - NW_BLK - NP_BLK) * 256 + threadIdx.x;    // 147,456
        const int total4 = NB * BATCH * HID / 4;
        if (idx >= total4) return;
        const int H4 = HID / 4;
        int h = (idx % H4) * 4;
        int b = (idx / H4) % BATCH;
        int n = idx / (H4 * BATCH);
        const int fs4 = NB * HID / 4;
        const float4* ph = (const float4*)(hid + ((size_t)b * TIN * NB + n) * HID + h);
        const float4* pc = (const float4*)(cel + ((size_t)b * TIN * NB + n) * HID + h);
        float sh[4] = {0,0,0,0}, sc[4] = {0,0,0,0};
        for (int t = 0; t < TIN; ++t) {
            float4 vh = ph[(size_t)t * fs4];
            float4 vc = pc[(size_t)t * fs4];
            sh[0] += vh.x; sh[1] += vh.y; sh[2] += vh.z; sh[3] += vh.w;
            sc[0] += vc.x; sc[1] += vc.y; sc[2] += vc.z; sc[3] += vc.w;
        }
        float4 g4 = *(const float4*)(gt + ((size_t)b * NB + n) * HID + h);
        const float* g_ = (const float*)&g4;
        unsigned short o0[4], o1[4];
        float c0[4];
#pragma unroll
        for (int j = 0; j < 4; ++j) {
            o0[j] = f2bf(sh[j] / TIN);
            o1[j] = f2bf((g_[j] + sh[j]) / (TIN + 1));
            c0[j] = sc[j] / TIN;
        }
        size_t base = (size_t)idx * 4;
        const size_t tot = (size_t)NB * BATCH * HID;
        *(uint2*)(hp_b + base)       = *(const uint2*)o0;
        *(uint2*)(hp_b + tot + base) = *(const uint2*)o1;
        *(float4*)(cp_f + base)       = make_float4(c0[0], c0[1], c0[2], c0[3]);
        *(float4*)(cp_f + tot + base) = make_float4(c0[0], c0[1], c0[2], c0[3]);
    }
}

// spatial boundary: mean over bones of the r=0 init states
__global__ void init_bounds_kernel(const unsigned short* __restrict__ hp_b,
                                   const float* __restrict__ cp_f,
                                   unsigned short* __restrict__ bh_b,
                                   float* __restrict__ bc_f) {
    int idx = blockIdx.x * blockDim.x + threadIdx.x;       // BATCH*HID
    if (idx >= BATCH * HID) return;
    float sh = 0.f, sc = 0.f;
    for (int n = 0; n < NB; ++n) {
        sh += bf2f(hp_b[(size_t)n * BATCH * HID + idx]);
        sc += cp_f[(size_t)n * BATCH * HID + idx];
    }
    bh_b[idx] = f2bf(sh / NB);
    bc_f[idx] = sc / NB;
}

__global__ void reset_kernel(int* done, int* tick) {
    int i = blockIdx.x * blockDim.x + threadIdx.x;
    if (i < 2 * NB * SOUT) done[i] = 0;
    if (i == 0) *tick = 0;
}

// ---------------------------------------------------------------------------
// Persistent dataflow kernel. PGRID blocks (2/CU, resident) x 640 threads
// (10 waves: gate=w%5, K-half=w/5). Work items = (cell r,n,f; col-tile t)
// pulled via a global ticket in topological order.
// Per item: (1) prefetch-touch this item's weights (dep-independent) so the
// memory system streams them during the dependency wait; (2) ONE thread
// spins on RELAXED loads + s_sleep, acquires once, barrier; (3) 4-deep
// software-pipelined MFMA loop (loads now mostly L2-warm); (4) epilogue,
// release-add of the per-cell done counter.
// ---------------------------------------------------------------------------
__global__ __launch_bounds__(640) void persist_kernel(
    const unsigned short* __restrict__ pb,
    const unsigned short* __restrict__ wpack,
    const float* __restrict__ bias,
    const unsigned short* __restrict__ hp_b,
    const float* __restrict__ cp_f,
    const unsigned short* __restrict__ bh_b,
    const float* __restrict__ bc_f,
    unsigned short* __restrict__ h_st,   // [2][NB][SOUT][64][384] bf16
    float* __restrict__ c_st,            // same shape f32
    float* __restrict__ out,
    int* __restrict__ done,              // [2*NB*SOUT]
    int* __restrict__ tick)
{
    const int wv   = threadIdx.x >> 6;
    const int gate = wv % NGATE;
    const int kh   = wv / NGATE;
    const int lane = threadIdx.x & 63;
    const int S = BATCH * HID;

    __shared__ int s_tkt;
    __shared__ float gl[2][NGATE][64][17];

    for (;;) {
        __syncthreads();
        if (threadIdx.x == 0)
            s_tkt = __hip_atomic_fetch_add(tick, 1, __ATOMIC_RELAXED,
                                           __HIP_MEMORY_SCOPE_AGENT);
        __syncthreads();
        const int T = s_tkt;
        if (T >= NITEMS) return;

        // ---- decode ticket -> (r, n, f, t) in topo order
        int rem = T, r = 0, lo = 0, d = 0;
        for (int s = 0;; ++s) {
            d = s >> 1; r = s & 1;
            lo = d - (SOUT - 1); if (lo < 0) lo = 0;
            int hi = (d < NB - 1) ? d : NB - 1;
            int c = (hi - lo + 1) * 24;
            if (rem < c) break;
            rem -= c;
        }
        const int n = lo + rem / 24;
        const int t = rem % 24;
        const int f = d - n;
        const int cell = r * NB + n;
        const int ci = cell * SOUT + f;

        const short8v* wpB = (const short8v*)wpack
            + (size_t)((cell * 24 + t) * NGATE + gate) * 36 * 64
            + (size_t)kh * 18 * 64 + lane;

        // ---- prefetch-touch weights (dep-independent) before dep wait:
        // streams next-stage weights into L2/L3 while this block waits.
        {
            const uint4* wt = (const uint4*)wpB;
            unsigned dx = 0, dy = 0, dz = 0, dw = 0;
#pragma unroll
            for (int s = 0; s < 18; ++s) {
                uint4 v = wt[(size_t)s * 64];
                dx ^= v.x; dy ^= v.y; dz ^= v.z; dw ^= v.w;
            }
            asm volatile("" :: "v"(dx), "v"(dy), "v"(dz), "v"(dw) : "memory");
        }

        // ---- dependency wait: single-thread relaxed polling + final acquire
        {
            int dep0 = -1, dep1 = -1, dep2 = -1;
            if (r == 0) {
                if (f > 0) dep0 = n * SOUT + f - 1;
                if (n > 0) dep1 = (n - 1) * SOUT + f;
            } else {
                dep0 = n * SOUT + f;
                if (f > 0) dep1 = (NB + n) * SOUT + f - 1;
                if (n > 0) dep2 = (NB + n - 1) * SOUT + f;
            }
            if (threadIdx.x == 0) {
                int deps[3] = { dep0, dep1, dep2 };
#pragma unroll
                for (int i = 0; i < 3; ++i) {
                    int dp = deps[i];
                    if (dp < 0) continue;
                    while (__hip_atomic_load(done + dp, __ATOMIC_RELAXED,
                                             __HIP_MEMORY_SCOPE_AGENT) < 24)
                        __builtin_amdgcn_s_sleep(8);
                    int z = __hip_atomic_load(done + dp, __ATOMIC_ACQUIRE,
                                              __HIP_MEMORY_SCOPE_AGENT);
                    asm volatile("" :: "v"(z));
                }
            }
            __syncthreads();
        }

        // ---- operand base pointers
        const unsigned short *xb, *htb, *hsb;
        const float *ctb, *csb;
        if (r == 0) {
            xb  = pb + (size_t)(f * NB + n) * S;
            htb = f ? h_st + (size_t)(n * SOUT + f - 1) * S : hp_b + (size_t)n * S;
            hsb = n ? h_st + (size_t)((n - 1) * SOUT + f) * S : bh_b;
            ctb = f ? c_st + (size_t)(n * SOUT + f - 1) * S : cp_f + (size_t)n * S;
            csb = n ? c_st + (size_t)((n - 1) * SOUT + f) * S : bc_f;
        } else {
            xb  = h_st + (size_t)(n * SOUT + f) * S;        // h0 of this cell
            htb = f ? h_st + (size_t)((NB + n) * SOUT + f - 1) * S
                    : hp_b + (size_t)(NB + n) * S;
            hsb = n ? h_st + (size_t)((NB + n - 1) * SOUT + f) * S : bh_b;
            ctb = f ? c_st + (size_t)((NB + n) * SOUT + f - 1) * S
                    : cp_f + (size_t)(NB + n) * S;
            csb = n ? c_st + (size_t)((NB + n - 1) * SOUT + f) * S : bc_f;
        }

        // ---- epilogue operands issued early (latency hides under MFMA)
        float4 ct4, cs4;
        float4 bg[NGATE];
        const int eb = threadIdx.x >> 2;
        const int ec0 = (threadIdx.x & 3) * 4;
        const int ecol = t * 16 + ec0;
        if (threadIdx.x < 256) {
            ct4 = *(const float4*)(ctb + (size_t)eb * HID + ecol);
            cs4 = *(const float4*)(csb + (size_t)eb * HID + ecol);
            const float* bbb = bias + (size_t)cell * NGATE * HID + ecol;
#pragma unroll
            for (int g = 0; g < NGATE; ++g) bg[g] = *(const float4*)(bbb + g * HID);
        }

        const int rl = lane & 15;
        const int kg = (lane >> 4) * 8;
        const unsigned short* s0 = xb  + (size_t)rl * HID + kg;
        const unsigned short* s1 = htb + (size_t)rl * HID + kg;
        const unsigned short* s2 = hsb + (size_t)rl * HID + kg;

        auto addrA = [&](int s) -> const unsigned short* {
            if (kh == 0) return (s < 12) ? s0 + s * 32 : s1 + (s - 12) * 32;
            else         return (s < 6)  ? s1 + (s + 6) * 32 : s2 + (s - 6) * 32;
        };

        f32x4 acc0 = {0,0,0,0}, acc1 = {0,0,0,0}, acc2 = {0,0,0,0}, acc3 = {0,0,0,0};

        constexpr int PF = 4;
        short8v bb[PF];
        short8v aa[PF][4];
#pragma unroll
        for (int s = 0; s < PF; ++s) {
            bb[s] = wpB[(size_t)s * 64];
            const unsigned short* ap = addrA(s);
            aa[s][0] = *(const short8v*)(ap);
            aa[s][1] = *(const short8v*)(ap + 16 * HID);
            aa[s][2] = *(const short8v*)(ap + 32 * HID);
            aa[s][3] = *(const short8v*)(ap + 48 * HID);
        }
#pragma unroll
        for (int s = 0; s < 18; ++s) {
            const int slot = s & (PF - 1);
            short8v b_ = bb[slot];
            acc0 = __builtin_amdgcn_mfma_f32_16x16x32_bf16(aa[slot][0], b_, acc0, 0, 0, 0);
            acc1 = __builtin_amdgcn_mfma_f32_16x16x32_bf16(aa[slot][1], b_, acc1, 0, 0, 0);
            acc2 = __builtin_amdgcn_mfma_f32_16x16x32_bf16(aa[slot][2], b_, acc2, 0, 0, 0);
            acc3 = __builtin_amdgcn_mfma_f32_16x16x32_bf16(aa[slot][3], b_, acc3, 0, 0, 0);
            if (s + PF < 18) {
                const int nx = s + PF;
                bb[slot] = wpB[(size_t)nx * 64];
                const unsigned short* ap = addrA(nx);
                aa[slot][0] = *(const short8v*)(ap);
                aa[slot][1] = *(const short8v*)(ap + 16 * HID);
                aa[slot][2] = *(const short8v*)(ap + 32 * HID);
                aa[slot][3] = *(const short8v*)(ap + 48 * HID);
            }
        }

        {
            int rb = (lane >> 4) * 4;
#pragma unroll
            for (int i = 0; i < 4; ++i) {
                gl[kh][gate][rb + i +  0][rl] = acc0[i];
                gl[kh][gate][rb + i + 16][rl] = acc1[i];
                gl[kh][gate][rb + i + 32][rl] = acc2[i];
                gl[kh][gate][rb + i + 48][rl] = acc3[i];
            }
        }
        __syncthreads();

        if (threadIdx.x < 256) {
            const float* ct_ = (const float*)&ct4;
            const float* cs_ = (const float*)&cs4;
            size_t doff = (size_t)ci * S + (size_t)eb * HID + ecol;
            unsigned short* hd = h_st + doff;
            float* cd = c_st + doff;

            float hv4[4], ch4[4];
#pragma unroll
            for (int cc = 0; cc < 4; ++cc) {
                int c = ec0 + cc;
                float gi  = gl[0][0][eb][c] + gl[1][0][eb][c] + ((const float*)&bg[0])[cc];
                float gfs = gl[0][1][eb][c] + gl[1][1][eb][c] + ((const float*)&bg[1])[cc];
                float gft = gl[0][2][eb][c] + gl[1][2][eb][c] + ((const float*)&bg[2])[cc];
                float go  = gl[0][3][eb][c] + gl[1][3][eb][c] + ((const float*)&bg[3])[cc];
                float gc  = gl[0][4][eb][c] + gl[1][4][eb][c] + ((const float*)&bg[4])[cc];
                float i_n = 1.f / (1.f + __expf(-gi));
                float f_s = 1.f / (1.f + __expf(-gfs));
                float f_t = 1.f / (1.f + __expf(-gft));
                float o_n = 1.f / (1.f + __expf(-go));
                float c_n = tanhf(gc);
                float ch  = i_n * c_n + f_t * ct_[cc] + f_s * cs_[cc];
                float hv  = o_n * tanhf(ch);
                hv4[cc] = hv; ch4[cc] = ch;
                hd[cc] = f2bf(hv);
            }
            *(float4*)cd = make_float4(ch4[0], ch4[1], ch4[2], ch4[3]);
            if (r == 1) {
                size_t o = ((size_t)(eb * SOUT + f) * NB + n) * HID + ecol;
                *(float4*)(out + o) = make_float4(hv4[0], hv4[1], hv4[2], hv4[3]);
                *(float4*)(out + (size_t)BATCH * SOUT * NB * HID + o)
                    = make_float4(ch4[0], ch4[1], ch4[2], ch4[3]);
            }
        }
        __syncthreads();
        if (threadIdx.x == 0)
            __hip_atomic_fetch_add(done + ci, 1, __ATOMIC_RELEASE,
                                   __HIP_MEMORY_SCOPE_AGENT);
    }
}

// ---------------------------------------------------------------------------
extern "C" void kernel_launch(void* const* d_in, const int* in_sizes, int n_in,
                              void* d_out, int out_size, void* d_ws, size_t ws_size,
                              hipStream_t stream) {
    const float* hid  = (const float*)d_in[0];
    const float* cel  = (const float*)d_in[1];
    const float* gt   = (const float*)d_in[2];
    // d_in[3] global_s_state: unused by the reference
    const float* p    = (const float*)d_in[4];
    const float* U    = (const float*)d_in[5];
    const float* Wt   = (const float*)d_in[6];
    const float* Ws   = (const float*)d_in[7];
    const float* bias = (const float*)d_in[8];
    float* out = (float*)d_out;

    char* cur_ = (char*)d_ws;
    auto carve = [&](size_t bytes) -> void* {
        void* r = cur_; cur_ += (bytes + 255) & ~(size_t)255; return r;
    };
    const size_t NPBH = (size_t)NB * BATCH * HID;
    unsigned short* wpack = (unsigned short*)carve((size_t)13271040 * 16); // 212 MB
    unsigned short* pb    = (unsigned short*)carve((size_t)SOUT * NB * BATCH * HID * 2);
    unsigned short* hp_b  = (unsigned short*)carve(2 * NPBH * 2);
    float*          cp_f  = (float*)carve(2 * NPBH * 4);
    unsigned short* bh_b  = (unsigned short*)carve((size_t)BATCH * HID * 2);
    float*          bc_f  = (float*)carve((size_t)BATCH * HID * 4);
    unsigned short* h_st  = (unsigned short*)carve((size_t)2 * NB * SOUT * BATCH * HID * 2);
    float*          c_st  = (float*)carve((size_t)2 * NB * SOUT * BATCH * HID * 4);
    int*            done  = (int*)carve(2 * NB * SOUT * sizeof(int));
    int*            tick  = (int*)carve(256);   // own cacheline

    reset_kernel<<<2, 256, 0, stream>>>(done, tick);
    prologue_kernel<<<NW_BLK + NP_BLK + NM_BLK, 256, 0, stream>>>(
        U, Wt, Ws, p, hid, cel, gt, wpack, pb, hp_b, cp_f);
    init_bounds_kernel<<<(BATCH * HID + 255) / 256, 256, 0, stream>>>(
        hp_b, cp_f, bh_b, bc_f);
    persist_kernel<<<PGRID, 640, 0, stream>>>(
        pb, wpack, bias, hp_b, cp_f, bh_b, bc_f,
        h_st, c_st, out, done, tick);
}

// Round 7
// 1268.160 us; speedup vs baseline: 3.8692x; 1.5750x over previous
//
#include <hip/hip_runtime.h>

#define BATCH 64
#define TIN   49
#define NB    24
#define HID   384
#define SOUT  10
#define NGATE 5

typedef __attribute__((ext_vector_type(4))) float f32x4;
typedef __attribute__((ext_vector_type(8))) short short8v;

__device__ __forceinline__ unsigned short f2bf(float f) {
    union { float f; unsigned u; } v; v.f = f;
    unsigned r = v.u + 0x7fffu + ((v.u >> 16) & 1u);   // round-nearest-even
    return (unsigned short)(r >> 16);
}
__device__ __forceinline__ float bf2f(unsigned short h) {
    union { unsigned u; float f; } v; v.u = ((unsigned)h) << 16; return v.f;
}

#define NW2_BLK 25920   // 48 cells * 5 gates * 3 mats * 36 (6 kb x 6 cb) tiles
#define NP_BLK  23040
#define NM_BLK  576

// ---------------------------------------------------------------------------
// Fused prologue: pack_w (LDS-transposed) + pack_p + init_means.
// wpack layout (short8 units): [(cell*12+t32)*5+g][kc=36][pair=2][lane=64]
//   kc = m*12 + kh*6 + j ; elem jj: B[k][col], k = kc*32+(lane>>4)*8+jj (within
//   source m), col = t32*32 + pair*16 + (lane&15).
// ---------------------------------------------------------------------------
__global__ __launch_bounds__(256) void prologue_kernel(
    const float* __restrict__ U, const float* __restrict__ Wt,
    const float* __restrict__ Ws, const float* __restrict__ p,
    const float* __restrict__ hid, const float* __restrict__ cel,
    const float* __restrict__ gt,
    unsigned short* __restrict__ wpack, unsigned short* __restrict__ pb,
    unsigned short* __restrict__ hp_b, float* __restrict__ cp_f)
{
    __shared__ unsigned short tile[64][68];
    int bx = blockIdx.x;
    if (bx < NW2_BLK) {
        int q = bx;
        int cb = q % 6; q /= 6;
        int kb = q % 6; q /= 6;
        int m  = q % 3; q /= 3;
        int g  = q % 5; q /= 5;
        int cell = q;                                  // 0..47 (r*NB+n)
        const float* W = (m == 0) ? U : (m == 1) ? Wt : Ws;
        const float* src = W + ((size_t)(cell * NGATE + g) * HID + kb * 64) * HID + cb * 64;
        int t = threadIdx.x;
        int kr = t >> 4, c4 = (t & 15) * 4;
#pragma unroll
        for (int i = 0; i < 4; ++i) {
            float4 v = *(const float4*)(src + (size_t)(kr + 16 * i) * HID + c4);
            tile[kr + 16 * i][c4 + 0] = f2bf(v.x);
            tile[kr + 16 * i][c4 + 1] = f2bf(v.y);
            tile[kr + 16 * i][c4 + 2] = f2bf(v.z);
            tile[kr + 16 * i][c4 + 3] = f2bf(v.w);
        }
        __syncthreads();
#pragma unroll
        for (int ii = 0; ii < 2; ++ii) {
            int e = t + 256 * ii;
            int lane = e & 63; int qq = e >> 6;        // 0..7
            int pair = qq & 1, kc2 = (qq >> 1) & 1, t2 = qq >> 2;
            int kl = kc2 * 32 + (lane >> 4) * 8;
            int cl = t2 * 32 + pair * 16 + (lane & 15);
            unsigned short o[8];
#pragma unroll
            for (int jj = 0; jj < 8; ++jj) o[jj] = tile[kl + jj][cl];
            int t32 = cb * 2 + t2;
            int kc  = m * 12 + kb * 2 + kc2;
            size_t dst = ((size_t)((cell * 12 + t32) * NGATE + g) * (36 * 2)
                          + kc * 2 + pair) * 64 + lane;
            *(short8v*)(wpack + dst * 8) = *(const short8v*)o;
        }
    } else if (bx < NW2_BLK + NP_BLK) {
        // p f32 [B][SOUT][NB][H] -> bf16 [SOUT][NB][B][H]
        size_t idx = (size_t)(bx - NW2_BLK) * 256 + threadIdx.x;  // 5,898,240
        int h = (int)(idx % HID);
        size_t q = idx / HID;
        int b = (int)(q % BATCH); q /= BATCH;
        int n = (int)(q % NB); q /= NB;
        int f = (int)q;
        pb[idx] = f2bf(p[((size_t)(b * SOUT + f) * NB + n) * HID + h]);
    } else {
        // temporal means -> hp (bf16) + cp (f32), layout [r][n][b][h]
        int idx = (bx - NW2_BLK - NP_BLK) * 256 + threadIdx.x;    // 147,456
        const int total4 = NB * BATCH * HID / 4;
        if (idx >= total4) return;
        const int H4 = HID / 4;
        int h = (idx % H4) * 4;
        int b = (idx / H4) % BATCH;
        int n = idx / (H4 * BATCH);
        const int fs4 = NB * HID / 4;
        const float4* ph = (const float4*)(hid + ((size_t)b * TIN * NB + n) * HID + h);
        const float4* pc = (const float4*)(cel + ((size_t)b * TIN * NB + n) * HID + h);
        float sh[4] = {0,0,0,0}, sc[4] = {0,0,0,0};
        for (int t = 0; t < TIN; ++t) {
            float4 vh = ph[(size_t)t * fs4];
            float4 vc = pc[(size_t)t * fs4];
            sh[0] += vh.x; sh[1] += vh.y; sh[2] += vh.z; sh[3] += vh.w;
            sc[0] += vc.x; sc[1] += vc.y; sc[2] += vc.z; sc[3] += vc.w;
        }
        float4 g4 = *(const float4*)(gt + ((size_t)b * NB + n) * HID + h);
        const float* g_ = (const float*)&g4;
        unsigned short o0[4], o1[4];
        float c0[4];
#pragma unroll
        for (int j = 0; j < 4; ++j) {
            o0[j] = f2bf(sh[j] / TIN);
            o1[j] = f2bf((g_[j] + sh[j]) / (TIN + 1));
            c0[j] = sc[j] / TIN;
        }
        size_t base = (size_t)idx * 4;
        const size_t tot = (size_t)NB * BATCH * HID;
        *(uint2*)(hp_b + base)       = *(const uint2*)o0;
        *(uint2*)(hp_b + tot + base) = *(const uint2*)o1;
        *(float4*)(cp_f + base)       = make_float4(c0[0], c0[1], c0[2], c0[3]);
        *(float4*)(cp_f + tot + base) = make_float4(c0[0], c0[1], c0[2], c0[3]);
    }
}

// spatial boundary: mean over bones of the r=0 init states
__global__ void init_bounds_kernel(const unsigned short* __restrict__ hp_b,
                                   const float* __restrict__ cp_f,
                                   unsigned short* __restrict__ bh_b,
                                   float* __restrict__ bc_f) {
    int idx = blockIdx.x * blockDim.x + threadIdx.x;       // BATCH*HID
    if (idx >= BATCH * HID) return;
    float sh = 0.f, sc = 0.f;
    for (int n = 0; n < NB; ++n) {
        sh += bf2f(hp_b[(size_t)n * BATCH * HID + idx]);
        sc += cp_f[(size_t)n * BATCH * HID + idx];
    }
    bh_b[idx] = f2bf(sh / NB);
    bc_f[idx] = sc / NB;
}

// ---------------------------------------------------------------------------
// Fused wavefront kernel (dispatch d = r0 cells diag d + r1 cells diag d-1).
// grid.x = 12 (32-col tiles), grid.y = A0+A1. Block 640 = 10 waves
// (gate = wv%5, kh = wv/5; each wave: 32 cols x K-half over 3 sources).
// A tiles staged in LDS (T14 split: load-early/write-late), shared by all
// 10 waves: 10x less A traffic. Gate-exchange LDS aliases the A buffers.
// ---------------------------------------------------------------------------
union SMem {
    unsigned short A[2][64][392];        // padded: +8 shorts per row -> 2-way banks
    float gl[2][NGATE][64][35];          // stride 35 (coprime 32) -> 2-way banks
};

__global__ __launch_bounds__(640) void cell_fused_kernel(
    int d, int A0,
    const unsigned short* __restrict__ pb,
    const unsigned short* __restrict__ wpack,
    const float* __restrict__ bias,
    const unsigned short* __restrict__ hp_b,
    const float* __restrict__ cp_f,
    const unsigned short* __restrict__ bh_b,
    const float* __restrict__ bc_f,
    unsigned short* __restrict__ h_sl,   // [par][r][NB][64][384] bf16
    float* __restrict__ c_sl,            // same shape f32
    float* __restrict__ out)
{
    __shared__ SMem sm;

    int y = blockIdx.y;
    int rstep, dg;
    if (y < A0) { rstep = 0; dg = d; }
    else        { rstep = 1; dg = d - 1; y -= A0; }
    int lo = dg - (SOUT - 1); if (lo < 0) lo = 0;
    const int n = lo + y;
    const int f = dg - n;
    const int cur = dg & 1, prv = cur ^ 1;
    const int t = blockIdx.x;            // 32-col tile, 0..11
    const int wv   = threadIdx.x >> 6;
    const int gate = wv % NGATE;
    const int kh   = wv / NGATE;
    const int lane = threadIdx.x & 63;
    const int S = BATCH * HID;
    const int cell = rstep * NB + n;

    const unsigned short *xb, *htb, *hsb;
    const float *ctb, *csb;
    if (rstep == 0) {
        xb  = pb + (size_t)(f * NB + n) * S;
        htb = f ? h_sl + (size_t)((prv * 2 + 0) * NB + n) * S : hp_b + (size_t)n * S;
        hsb = n ? h_sl + (size_t)((prv * 2 + 0) * NB + n - 1) * S : bh_b;
        ctb = f ? c_sl + (size_t)((prv * 2 + 0) * NB + n) * S : cp_f + (size_t)n * S;
        csb = n ? c_sl + (size_t)((prv * 2 + 0) * NB + n - 1) * S : bc_f;
    } else {
        xb  = h_sl + (size_t)((cur * 2 + 0) * NB + n) * S;   // h0 of this cell
        htb = f ? h_sl + (size_t)((prv * 2 + 1) * NB + n) * S
                : hp_b + (size_t)(NB + n) * S;
        hsb = n ? h_sl + (size_t)((prv * 2 + 1) * NB + n - 1) * S : bh_b;
        ctb = f ? c_sl + (size_t)((prv * 2 + 1) * NB + n) * S
                : cp_f + (size_t)(NB + n) * S;
        csb = n ? c_sl + (size_t)((prv * 2 + 1) * NB + n - 1) * S : bc_f;
    }

    // ---- hoist epilogue cell-state loads (latency hides under MFMA)
    const int eb = threadIdx.x & 63;
    const int ecq = (threadIdx.x >> 6) & 3;
    float4 cth[2], csh[2];
    if (threadIdx.x < 256) {
#pragma unroll
        for (int h = 0; h < 2; ++h) {
            int colg = t * 32 + h * 16 + ecq * 4;
            cth[h] = *(const float4*)(ctb + (size_t)eb * HID + colg);
            csh[h] = *(const float4*)(csb + (size_t)eb * HID + colg);
        }
    }

    // ---- staging machinery: 64x384 bf16 = 3072 16B-chunks, 640 threads
    uint4 streg[5];
    auto STAGE_LOAD = [&](const unsigned short* src) {
#pragma unroll
        for (int i = 0; i < 5; ++i) {
            int c = (int)threadIdx.x + i * 640;
            if (i < 4 || c < 3072) {
                int row = c / 48, cc = c - row * 48;
                streg[i] = *(const uint4*)(src + (size_t)row * HID + cc * 8);
            }
        }
    };
    auto STAGE_WRITE = [&](int buf) {
#pragma unroll
        for (int i = 0; i < 5; ++i) {
            int c = (int)threadIdx.x + i * 640;
            if (i < 4 || c < 3072) {
                int row = c / 48, cc = c - row * 48;
                *(uint4*)&sm.A[buf][row][cc * 8] = streg[i];
            }
        }
    };

    const short8v* wp = (const short8v*)wpack
        + (size_t)((cell * 12 + t) * NGATE + gate) * (36 * 2 * 64);

    f32x4 acc[2][4];
#pragma unroll
    for (int pr = 0; pr < 2; ++pr)
#pragma unroll
        for (int q = 0; q < 4; ++q) acc[pr][q] = (f32x4){0, 0, 0, 0};

    const int arow = lane & 15;
    const int akg  = (lane >> 4) * 8;

    auto COMPUTE = [&](int m, int buf) {
        const short8v* wbm = wp + (size_t)((m * 12 + kh * 6) * 2) * 64 + lane;
        short8v bufB[3][2];
#pragma unroll
        for (int j = 0; j < 3; ++j) {
            bufB[j][0] = wbm[(size_t)j * 128];
            bufB[j][1] = wbm[(size_t)j * 128 + 64];
        }
#pragma unroll
        for (int j = 0; j < 6; ++j) {
            const int koff = kh * 192 + j * 32 + akg;
            short8v a[4];
#pragma unroll
            for (int q = 0; q < 4; ++q)
                a[q] = *(const short8v*)&sm.A[buf][arow + q * 16][koff];
            const int sl = j % 3;
#pragma unroll
            for (int q = 0; q < 4; ++q) {
                acc[0][q] = __builtin_amdgcn_mfma_f32_16x16x32_bf16(a[q], bufB[sl][0], acc[0][q], 0, 0, 0);
                acc[1][q] = __builtin_amdgcn_mfma_f32_16x16x32_bf16(a[q], bufB[sl][1], acc[1][q], 0, 0, 0);
            }
            if (j < 3) {
                bufB[sl][0] = wbm[(size_t)(j + 3) * 128];
                bufB[sl][1] = wbm[(size_t)(j + 3) * 128 + 64];
            }
        }
    };

    // ---- pipeline: stage(0); [load(1) | compute(0)]; [load(2) | compute(1)]; compute(2)
    STAGE_LOAD(xb);
    STAGE_WRITE(0);
    __syncthreads();

    STAGE_LOAD(htb);
    COMPUTE(0, 0);
    __syncthreads();
    STAGE_WRITE(1);
    __syncthreads();

    STAGE_LOAD(hsb);
    COMPUTE(1, 1);
    __syncthreads();
    STAGE_WRITE(0);
    __syncthreads();

    COMPUTE(2, 0);
    __syncthreads();                     // A reads done; gl may alias A

    // ---- gate exchange
#pragma unroll
    for (int pr = 0; pr < 2; ++pr)
#pragma unroll
        for (int q = 0; q < 4; ++q)
#pragma unroll
            for (int i = 0; i < 4; ++i)
                sm.gl[kh][gate][q * 16 + (lane >> 4) * 4 + i][pr * 16 + (lane & 15)]
                    = acc[pr][q][i];
    __syncthreads();

    // ---- fused epilogue (256 threads, b = tid&63 -> stride-35 reads, 2-way)
    if (threadIdx.x < 256) {
        size_t dbase = (size_t)((cur * 2 + rstep) * NB + n) * S + (size_t)eb * HID;
        const float* bbase = bias + (size_t)cell * NGATE * HID;
#pragma unroll
        for (int h = 0; h < 2; ++h) {
            int cloc = h * 16 + ecq * 4;
            int colg = t * 32 + cloc;
            const float* ct_ = (const float*)&cth[h];
            const float* cs_ = (const float*)&csh[h];
            float hv4[4], ch4[4];
            unsigned short hb4[4];
#pragma unroll
            for (int cc = 0; cc < 4; ++cc) {
                float gi  = sm.gl[0][0][eb][cloc + cc] + sm.gl[1][0][eb][cloc + cc] + bbase[0 * HID + colg + cc];
                float gfs = sm.gl[0][1][eb][cloc + cc] + sm.gl[1][1][eb][cloc + cc] + bbase[1 * HID + colg + cc];
                float gft = sm.gl[0][2][eb][cloc + cc] + sm.gl[1][2][eb][cloc + cc] + bbase[2 * HID + colg + cc];
                float go  = sm.gl[0][3][eb][cloc + cc] + sm.gl[1][3][eb][cloc + cc] + bbase[3 * HID + colg + cc];
                float gc  = sm.gl[0][4][eb][cloc + cc] + sm.gl[1][4][eb][cloc + cc] + bbase[4 * HID + colg + cc];
                float i_n = 1.f / (1.f + __expf(-gi));
                float f_s = 1.f / (1.f + __expf(-gfs));
                float f_t = 1.f / (1.f + __expf(-gft));
                float o_n = 1.f / (1.f + __expf(-go));
                float c_n = tanhf(gc);
                float ch  = i_n * c_n + f_t * ct_[cc] + f_s * cs_[cc];
                float hv  = o_n * tanhf(ch);
                hv4[cc] = hv; ch4[cc] = ch; hb4[cc] = f2bf(hv);
            }
            *(uint2*)(h_sl + dbase + colg) = *(const uint2*)hb4;
            *(float4*)(c_sl + dbase + colg) = make_float4(ch4[0], ch4[1], ch4[2], ch4[3]);
            if (rstep == 1) {
                size_t o = ((size_t)(eb * SOUT + f) * NB + n) * HID + colg;
                *(float4*)(out + o) = make_float4(hv4[0], hv4[1], hv4[2], hv4[3]);
                *(float4*)(out + (size_t)BATCH * SOUT * NB * HID + o)
                    = make_float4(ch4[0], ch4[1], ch4[2], ch4[3]);
            }
        }
    }
}

// ---------------------------------------------------------------------------
extern "C" void kernel_launch(void* const* d_in, const int* in_sizes, int n_in,
                              void* d_out, int out_size, void* d_ws, size_t ws_size,
                              hipStream_t stream) {
    const float* hid  = (const float*)d_in[0];
    const float* cel  = (const float*)d_in[1];
    const float* gt   = (const float*)d_in[2];
    // d_in[3] global_s_state: unused by the reference
    const float* p    = (const float*)d_in[4];
    const float* U    = (const float*)d_in[5];
    const float* Wt   = (const float*)d_in[6];
    const float* Ws   = (const float*)d_in[7];
    const float* bias = (const float*)d_in[8];
    float* out = (float*)d_out;

    char* cur_ = (char*)d_ws;
    auto carve = [&](size_t bytes) -> void* {
        void* r = cur_; cur_ += (bytes + 255) & ~(size_t)255; return r;
    };
    const size_t NPBH = (size_t)NB * BATCH * HID;
    unsigned short* wpack = (unsigned short*)carve((size_t)13271040 * 16); // 212 MB
    unsigned short* pb    = (unsigned short*)carve((size_t)SOUT * NB * BATCH * HID * 2);
    unsigned short* hp_b  = (unsigned short*)carve(2 * NPBH * 2);
    float*          cp_f  = (float*)carve(2 * NPBH * 4);
    unsigned short* bh_b  = (unsigned short*)carve((size_t)BATCH * HID * 2);
    float*          bc_f  = (float*)carve((size_t)BATCH * HID * 4);
    unsigned short* h_sl  = (unsigned short*)carve(4 * NPBH * 2);
    float*          c_sl  = (float*)carve(4 * NPBH * 4);

    prologue_kernel<<<NW2_BLK + NP_BLK + NM_BLK, 256, 0, stream>>>(
        U, Wt, Ws, p, hid, cel, gt, wpack, pb, hp_b, cp_f);
    init_bounds_kernel<<<(BATCH * HID + 255) / 256, 256, 0, stream>>>(
        hp_b, cp_f, bh_b, bc_f);

    auto cnt = [](int dg) {
        int lo = dg - (SOUT - 1); if (lo < 0) lo = 0;
        int hi = (dg < NB - 1) ? dg : NB - 1;
        return hi - lo + 1;
    };
    for (int d = 0; d < SOUT + NB; ++d) {          // 34 dispatches
        int A0 = (d <= SOUT + NB - 2) ? cnt(d) : 0;
        int A1 = (d >= 1) ? cnt(d - 1) : 0;
        dim3 grid(12, A0 + A1);
        cell_fused_kernel<<<grid, 640, 0, stream>>>(d, A0, pb, wpack, bias,
                                                    hp_b, cp_f, bh_b, bc_f,
                                                    h_sl, c_sl, out);
    }
}